// Round 4
// baseline (161.863 us; speedup 1.0000x reference)
//
#include <hip/hip_runtime.h>
#include <hip/hip_bf16.h>
#include <math.h>

// Problem constants (AttentionDecoder: B,C,H,W = 4,256,64,64)
#define BB 4
#define CC 256
#define C8 32
#define HH 64
#define WW 64
#define NN 4096   // HH*WW
#define QBLK 32
#define KBLK 128

typedef __attribute__((ext_vector_type(8))) short bh8;   // 8 x bf16 (4 VGPR)
typedef __attribute__((ext_vector_type(4))) float f4;    // MFMA accumulator

static __device__ __forceinline__ float bf2f(unsigned short u) {
    union { unsigned int u; float f; } v; v.u = ((unsigned int)u) << 16;
    return v.f;
}
static __device__ __forceinline__ unsigned short f2bf(float f) {
    union { float f; unsigned int u; } v; v.f = f;
    return (unsigned short)((v.u + 0x7FFFu + ((v.u >> 16) & 1u)) >> 16);
}

// ---------------------------------------------------------------------------
// Kernel 0: pack [Wq;Wk;Wv] -> bf16 wb[320][256]
// ---------------------------------------------------------------------------
__global__ __launch_bounds__(256) void wconv_kernel(
    const float* __restrict__ Wq, const float* __restrict__ Wk,
    const float* __restrict__ Wv, unsigned short* __restrict__ wb)
{
    int f = (blockIdx.x * 256 + threadIdx.x) * 4;   // element index, < 81920
    const float* src;
    if (f < 32 * 256)           src = Wq + f;
    else if (f < 64 * 256)      src = Wk + (f - 32 * 256);
    else                        src = Wv + (f - 64 * 256);
    float4 v = *reinterpret_cast<const float4*>(src);
    ushort4 o;
    o.x = f2bf(v.x); o.y = f2bf(v.y); o.z = f2bf(v.z); o.w = f2bf(v.w);
    *reinterpret_cast<ushort4*>(wb + f) = o;
}

// ---------------------------------------------------------------------------
// Kernel 1: fused Q/K/V projection GEMM (MFMA). (unchanged from round 3)
// ---------------------------------------------------------------------------
__global__ __launch_bounds__(640, 1) void proj_kernel(
    const float* __restrict__ x, const float* __restrict__ xe,
    const unsigned short* __restrict__ wb,
    const float* __restrict__ bq, const float* __restrict__ bk,
    const float* __restrict__ bv,
    const float* __restrict__ hp, const float* __restrict__ wp,
    unsigned short* __restrict__ qb, unsigned short* __restrict__ kb,
    unsigned short* __restrict__ vv)
{
    const int b  = blockIdx.x & 3;
    const int n0 = (blockIdx.x >> 2) << 6;
    const int t  = threadIdx.x;
    const int w  = t >> 6;                 // 0..9
    const int lane = t & 63;
    const int l15 = lane & 15, l4 = lane >> 4;

    __shared__ unsigned short xT[64][256];   // [n][c^swz]  32 KB
    __shared__ unsigned short xeT[64][256];  // 32 KB

    bh8 af[2][8];
    {
        const unsigned short* wrow = wb + (size_t)(w * 32 + l15) * 256 + l4 * 8;
        #pragma unroll
        for (int kk = 0; kk < 8; ++kk) {
            af[0][kk] = *reinterpret_cast<const bh8*>(wrow + kk * 32);
            af[1][kk] = *reinterpret_cast<const bh8*>(wrow + 16 * 256 + kk * 32);
        }
    }

    {
        const float* xb  = x  + (size_t)(b * CC) * NN + n0;
        const float* xeb = xe + (size_t)(b * CC) * NN + n0;
        for (int i = t; i < 4096; i += 640) {
            int c = i >> 4, n4 = (i & 15) << 2;
            float4 a = *reinterpret_cast<const float4*>(xb  + (size_t)c * NN + n4);
            float4 e = *reinterpret_cast<const float4*>(xeb + (size_t)c * NN + n4);
            #pragma unroll
            for (int j = 0; j < 4; ++j) {
                int n  = n4 + j;
                int cs = c ^ ((n & 7) << 3);
                xT[n][cs]  = f2bf((&a.x)[j]);
                xeT[n][cs] = f2bf((&e.x)[j]);
            }
        }
    }
    __syncthreads();

    const unsigned short* lds = (w == 0) ? &xT[0][0] : &xeT[0][0];
    f4 acc[2][4] = {};
    #pragma unroll
    for (int kk = 0; kk < 8; ++kk) {
        bh8 bf[4];
        #pragma unroll
        for (int nf = 0; nf < 4; ++nf) {
            int n  = nf * 16 + l15;
            int c0 = (kk * 32 + l4 * 8) ^ ((n & 7) << 3);
            bf[nf] = *reinterpret_cast<const bh8*>(lds + n * 256 + c0);
        }
        #pragma unroll
        for (int nf = 0; nf < 4; ++nf) {
            acc[0][nf] = __builtin_amdgcn_mfma_f32_16x16x32_bf16(af[0][kk], bf[nf], acc[0][nf], 0, 0, 0);
            acc[1][nf] = __builtin_amdgcn_mfma_f32_16x16x32_bf16(af[1][kk], bf[nf], acc[1][nf], 0, 0, 0);
        }
    }

    if (w < 2) {
        unsigned short* dst = (w == 0 ? qb : kb) + (size_t)(b * NN) * C8;
        const float* bias = (w == 0) ? bq : bk;
        #pragma unroll
        for (int mf = 0; mf < 2; ++mf) {
            #pragma unroll
            for (int nf = 0; nf < 4; ++nf) {
                int n  = n0 + nf * 16 + l15;
                int oo = mf * 16 + l4 * 4;
                ushort4 pk;
                #pragma unroll
                for (int r = 0; r < 4; ++r) {
                    int o = oo + r;
                    float val = acc[mf][nf][r] + bias[o];
                    if (w == 1) val += hp[o * HH + (n >> 6)] + wp[o * WW + (n & 63)];
                    (&pk.x)[r] = f2bf(val);
                }
                *reinterpret_cast<ushort4*>(dst + (size_t)n * C8 + oo) = pk;
            }
        }
    } else {
        #pragma unroll
        for (int mf = 0; mf < 2; ++mf) {
            int cb = (w - 2) * 32 + mf * 16 + l4 * 4;
            #pragma unroll
            for (int r = 0; r < 4; ++r) {
                float bvv = bv[cb + r];
                #pragma unroll
                for (int nf = 0; nf < 4; ++nf) {
                    int n = n0 + nf * 16 + l15;
                    vv[(size_t)(b * CC + cb + r) * NN + n] = f2bf(acc[mf][nf][r] + bvv);
                }
            }
        }
    }
}

// ---------------------------------------------------------------------------
// Kernel 2: MFMA flash attention + fused epilogue  out = gamma*(P@V^T/l) + x
// QBLK=32 q-rows/block (grid 512 -> 2 blocks/CU), KBLK=128 keys/iter.
// 512 thr = 8 waves. Wave w: QK^T frags (qg=w>>2, ng=2(w&3)+{0,1});
// softmax rows 4w..4w+3 (16 lanes/row, 8 cols each); PV channels [w*32,w*32+32).
// S[32][128] f32 (col ^= 4(q&7)); P[32][128] bf16 single-buffered
// (16B-granule col ^= 8(q&7)); 2 barriers / 128 keys.
// ---------------------------------------------------------------------------
__global__ __launch_bounds__(512, 4) void attn_mfma_kernel(
    const unsigned short* __restrict__ qb, const unsigned short* __restrict__ kb,
    const unsigned short* __restrict__ v,  const float* __restrict__ x,
    const float* __restrict__ gamma, float* __restrict__ out)
{
    const int b    = blockIdx.x & 3;
    const int r0   = (blockIdx.x >> 2) << 5;    // q-tile base (32 rows)
    const int t    = threadIdx.x;
    const int w    = t >> 6;
    const int lane = t & 63;
    const int l15  = lane & 15, l4 = lane >> 4;
    const int qg   = w >> 2;                    // 0 or 1
    const int ng0  = (w & 3) * 2;               // 0,2,4,6

    __shared__ __align__(16) float S[32][128];              // 16 KB
    __shared__ __align__(16) unsigned short P[32][128];     // 8 KB
    __shared__ float a_lds[32];
    __shared__ float l_lds[32];

    // Q fragment (A-operand), held for whole kernel
    const bh8 qf = *reinterpret_cast<const bh8*>(
        qb + ((size_t)(b * NN) + r0 + qg * 16 + l15) * C8 + 8 * l4);

    // K base (B-operand, frags ng0 and ng0+1)
    const unsigned short* kbase = kb + ((size_t)(b * NN) + ng0 * 16 + l15) * C8 + 8 * l4;
    // V base: channel c = w*32 + cgi*16 + l15, key col tt*KBLK + ks*32 + 8*l4
    const unsigned short* vbase = v + ((size_t)(b * CC) + w * 32 + l15) * NN + 8 * l4;

    // softmax mapping: 4 rows/wave, 16 lanes/row, 8 cols/lane
    const int srow = 4 * w + (lane >> 4);
    const int sa   = lane & 15;
    const int sswz = 4 * (srow & 7);
    const int pcol = 8 * (sa ^ (srow & 7));
    float m_reg = -INFINITY, l_reg = 0.f;

    f4 acc[2][2] = {};   // [qgi][cgi]

    bh8 kf0 = *reinterpret_cast<const bh8*>(kbase);
    bh8 kf1 = *reinterpret_cast<const bh8*>(kbase + 16 * C8);

    for (int tt = 0; tt < NN / KBLK; ++tt) {
        // ---- QK^T ----
        f4 z = {0.f, 0.f, 0.f, 0.f};
        f4 s0 = __builtin_amdgcn_mfma_f32_16x16x32_bf16(qf, kf0, z, 0, 0, 0);
        f4 s1 = __builtin_amdgcn_mfma_f32_16x16x32_bf16(qf, kf1, z, 0, 0, 0);
        if (tt + 1 < NN / KBLK) {   // prefetch next K tile
            const unsigned short* kn = kbase + (size_t)(tt + 1) * KBLK * C8;
            kf0 = *reinterpret_cast<const bh8*>(kn);
            kf1 = *reinterpret_cast<const bh8*>(kn + 16 * C8);
        }
        #pragma unroll
        for (int r = 0; r < 4; ++r) {
            int q   = qg * 16 + l4 * 4 + r;
            int swz = 4 * (q & 7);
            S[q][(ng0 * 16 + l15) ^ swz]       = s0[r];
            S[q][((ng0 + 1) * 16 + l15) ^ swz] = s1[r];
        }
        __syncthreads();   // b1: S complete

        // prefetch V for this tile (latency hidden under softmax)
        bh8 vf[2][4];
        {
            const unsigned short* vt0 = vbase + (size_t)tt * KBLK;
            #pragma unroll
            for (int cgi = 0; cgi < 2; ++cgi)
                #pragma unroll
                for (int ks = 0; ks < 4; ++ks)
                    vf[cgi][ks] = *reinterpret_cast<const bh8*>(vt0 + cgi * 16 * NN + ks * 32);
        }

        // ---- online softmax ----
        f4 sv0 = *reinterpret_cast<const f4*>(&S[srow][(8 * sa) ^ sswz]);
        f4 sv1 = *reinterpret_cast<const f4*>(&S[srow][(8 * sa + 4) ^ sswz]);
        float tmax = fmaxf(fmaxf(fmaxf(sv0[0], sv0[1]), fmaxf(sv0[2], sv0[3])),
                           fmaxf(fmaxf(sv1[0], sv1[1]), fmaxf(sv1[2], sv1[3])));
        tmax = fmaxf(tmax, __shfl_xor(tmax, 1));
        tmax = fmaxf(tmax, __shfl_xor(tmax, 2));
        tmax = fmaxf(tmax, __shfl_xor(tmax, 4));
        tmax = fmaxf(tmax, __shfl_xor(tmax, 8));
        float mn    = fmaxf(m_reg, tmax);
        float alpha = __expf(m_reg - mn);
        float p0 = __expf(sv0[0] - mn), p1 = __expf(sv0[1] - mn);
        float p2 = __expf(sv0[2] - mn), p3 = __expf(sv0[3] - mn);
        float p4 = __expf(sv1[0] - mn), p5 = __expf(sv1[1] - mn);
        float p6 = __expf(sv1[2] - mn), p7 = __expf(sv1[3] - mn);
        float rs = ((p0 + p1) + (p2 + p3)) + ((p4 + p5) + (p6 + p7));
        rs += __shfl_xor(rs, 1);
        rs += __shfl_xor(rs, 2);
        rs += __shfl_xor(rs, 4);
        rs += __shfl_xor(rs, 8);
        l_reg = l_reg * alpha + rs;
        m_reg = mn;
        if (sa == 0) a_lds[srow] = alpha;
        bh8 pb;
        pb[0] = (short)f2bf(p0); pb[1] = (short)f2bf(p1);
        pb[2] = (short)f2bf(p2); pb[3] = (short)f2bf(p3);
        pb[4] = (short)f2bf(p4); pb[5] = (short)f2bf(p5);
        pb[6] = (short)f2bf(p6); pb[7] = (short)f2bf(p7);
        *reinterpret_cast<bh8*>(&P[srow][pcol]) = pb;
        __syncthreads();   // b2: P + a_lds complete

        // ---- rescale ----
        f4 al0 = *reinterpret_cast<const f4*>(&a_lds[l4 * 4]);
        f4 al1 = *reinterpret_cast<const f4*>(&a_lds[16 + l4 * 4]);
        #pragma unroll
        for (int cgi = 0; cgi < 2; ++cgi) {
            #pragma unroll
            for (int r = 0; r < 4; ++r) {
                acc[0][cgi][r] *= al0[r];
                acc[1][cgi][r] *= al1[r];
            }
        }

        // ---- PV ----
        const int pswz = 8 * (l15 & 7);
        __builtin_amdgcn_s_setprio(1);
        #pragma unroll
        for (int ks = 0; ks < 4; ++ks) {
            bh8 pa0 = *reinterpret_cast<const bh8*>(&P[l15]     [(32 * ks + 8 * l4) ^ pswz]);
            bh8 pa1 = *reinterpret_cast<const bh8*>(&P[16 + l15][(32 * ks + 8 * l4) ^ pswz]);
            acc[0][0] = __builtin_amdgcn_mfma_f32_16x16x32_bf16(pa0, vf[0][ks], acc[0][0], 0, 0, 0);
            acc[0][1] = __builtin_amdgcn_mfma_f32_16x16x32_bf16(pa0, vf[1][ks], acc[0][1], 0, 0, 0);
            acc[1][0] = __builtin_amdgcn_mfma_f32_16x16x32_bf16(pa1, vf[0][ks], acc[1][0], 0, 0, 0);
            acc[1][1] = __builtin_amdgcn_mfma_f32_16x16x32_bf16(pa1, vf[1][ks], acc[1][1], 0, 0, 0);
        }
        __builtin_amdgcn_s_setprio(0);
        // no barrier: next-iter S writes race nothing (P-reads of tile tt all
        // precede b1(tt+1); S only read between b1(tt) and b2(tt))
    }

    // ---- epilogue: out = gamma*(acc/l) + x ----
    if (sa == 0) l_lds[srow] = l_reg;
    __syncthreads();
    const float g = gamma[0];
    f4 lv0 = *reinterpret_cast<const f4*>(&l_lds[l4 * 4]);
    f4 lv1 = *reinterpret_cast<const f4*>(&l_lds[16 + l4 * 4]);
    f4 li0, li1;
    #pragma unroll
    for (int r = 0; r < 4; ++r) { li0[r] = 1.f / lv0[r]; li1[r] = 1.f / lv1[r]; }
    #pragma unroll
    for (int qgi = 0; qgi < 2; ++qgi) {
        f4 li = qgi ? li1 : li0;
        #pragma unroll
        for (int cgi = 0; cgi < 2; ++cgi) {
            int c = w * 32 + cgi * 16 + l15;
            size_t idx = ((size_t)(b * CC) + c) * NN + r0 + qgi * 16 + l4 * 4;
            float4 xr = *reinterpret_cast<const float4*>(x + idx);
            float4 o4;
            o4.x = g * (acc[qgi][cgi][0] * li[0]) + xr.x;
            o4.y = g * (acc[qgi][cgi][1] * li[1]) + xr.y;
            o4.z = g * (acc[qgi][cgi][2] * li[2]) + xr.z;
            o4.w = g * (acc[qgi][cgi][3] * li[3]) + xr.w;
            *reinterpret_cast<float4*>(out + idx) = o4;
        }
    }
}

// ---------------------------------------------------------------------------
extern "C" void kernel_launch(void* const* d_in, const int* in_sizes, int n_in,
                              void* d_out, int out_size, void* d_ws, size_t ws_size,
                              hipStream_t stream)
{
    (void)in_sizes; (void)n_in; (void)out_size; (void)ws_size;

    const float* x   = (const float*)d_in[0];
    const float* xe  = (const float*)d_in[1];
    const float* Wq  = (const float*)d_in[2];
    const float* bq  = (const float*)d_in[3];
    const float* Wk  = (const float*)d_in[4];
    const float* bk  = (const float*)d_in[5];
    const float* Wv  = (const float*)d_in[6];
    const float* bv  = (const float*)d_in[7];
    const float* hp  = (const float*)d_in[8];
    const float* wp  = (const float*)d_in[9];
    const float* gam = (const float*)d_in[10];
    float* out = (float*)d_out;

    // workspace: qb bf16 [B][N][32] (1MB) | kb (1MB) | v bf16 [B][C][N] (8MB) | wb bf16 [320][256] (160KB)
    char* ws = (char*)d_ws;
    unsigned short* qb = (unsigned short*)ws;
    unsigned short* kb = (unsigned short*)(ws + (size_t)BB * NN * C8 * 2);
    unsigned short* v  = (unsigned short*)(ws + 2 * (size_t)BB * NN * C8 * 2);
    unsigned short* wbuf = (unsigned short*)(ws + 2 * (size_t)BB * NN * C8 * 2
                                                + (size_t)BB * CC * NN * 2);

    wconv_kernel<<<80, 256, 0, stream>>>(Wq, Wk, Wv, wbuf);
    proj_kernel<<<BB * (NN / 64), 640, 0, stream>>>(x, xe, wbuf, bq, bk, bv, hp, wp, qb, kb, v);
    attn_mfma_kernel<<<BB * (NN / QBLK), 512, 0, stream>>>(qb, kb, v, x, gam, out);
}

// Round 5
// 161.294 us; speedup vs baseline: 1.0035x; 1.0035x over previous
//
#include <hip/hip_runtime.h>
#include <hip/hip_bf16.h>
#include <math.h>

// Problem constants (AttentionDecoder: B,C,H,W = 4,256,64,64)
#define BB 4
#define CC 256
#define C8 32
#define HH 64
#define WW 64
#define NN 4096   // HH*WW
#define QBLK 32
#define KBLK 64

typedef __attribute__((ext_vector_type(8))) short bh8;   // 8 x bf16 (4 VGPR)
typedef __attribute__((ext_vector_type(4))) float f4;    // MFMA accumulator

static __device__ __forceinline__ float bf2f(unsigned short u) {
    union { unsigned int u; float f; } v; v.u = ((unsigned int)u) << 16;
    return v.f;
}
static __device__ __forceinline__ unsigned short f2bf(float f) {
    union { float f; unsigned int u; } v; v.f = f;
    return (unsigned short)((v.u + 0x7FFFu + ((v.u >> 16) & 1u)) >> 16);
}

// ---------------------------------------------------------------------------
// Kernel 0: pack [Wq;Wk;Wv] -> bf16 wb[320][256]
// ---------------------------------------------------------------------------
__global__ __launch_bounds__(256) void wconv_kernel(
    const float* __restrict__ Wq, const float* __restrict__ Wk,
    const float* __restrict__ Wv, unsigned short* __restrict__ wb)
{
    int f = (blockIdx.x * 256 + threadIdx.x) * 4;   // element index, < 81920
    const float* src;
    if (f < 32 * 256)           src = Wq + f;
    else if (f < 64 * 256)      src = Wk + (f - 32 * 256);
    else                        src = Wv + (f - 64 * 256);
    float4 v = *reinterpret_cast<const float4*>(src);
    ushort4 o;
    o.x = f2bf(v.x); o.y = f2bf(v.y); o.z = f2bf(v.z); o.w = f2bf(v.w);
    *reinterpret_cast<ushort4*>(wb + f) = o;
}

// ---------------------------------------------------------------------------
// Kernel 1: fused Q/K/V projection GEMM (MFMA). (unchanged from round 3)
// ---------------------------------------------------------------------------
__global__ __launch_bounds__(640, 1) void proj_kernel(
    const float* __restrict__ x, const float* __restrict__ xe,
    const unsigned short* __restrict__ wb,
    const float* __restrict__ bq, const float* __restrict__ bk,
    const float* __restrict__ bv,
    const float* __restrict__ hp, const float* __restrict__ wp,
    unsigned short* __restrict__ qb, unsigned short* __restrict__ kb,
    unsigned short* __restrict__ vv)
{
    const int b  = blockIdx.x & 3;
    const int n0 = (blockIdx.x >> 2) << 6;
    const int t  = threadIdx.x;
    const int w  = t >> 6;                 // 0..9
    const int lane = t & 63;
    const int l15 = lane & 15, l4 = lane >> 4;

    __shared__ unsigned short xT[64][256];   // [n][c^swz]  32 KB
    __shared__ unsigned short xeT[64][256];  // 32 KB

    bh8 af[2][8];
    {
        const unsigned short* wrow = wb + (size_t)(w * 32 + l15) * 256 + l4 * 8;
        #pragma unroll
        for (int kk = 0; kk < 8; ++kk) {
            af[0][kk] = *reinterpret_cast<const bh8*>(wrow + kk * 32);
            af[1][kk] = *reinterpret_cast<const bh8*>(wrow + 16 * 256 + kk * 32);
        }
    }

    {
        const float* xb  = x  + (size_t)(b * CC) * NN + n0;
        const float* xeb = xe + (size_t)(b * CC) * NN + n0;
        for (int i = t; i < 4096; i += 640) {
            int c = i >> 4, n4 = (i & 15) << 2;
            float4 a = *reinterpret_cast<const float4*>(xb  + (size_t)c * NN + n4);
            float4 e = *reinterpret_cast<const float4*>(xeb + (size_t)c * NN + n4);
            #pragma unroll
            for (int j = 0; j < 4; ++j) {
                int n  = n4 + j;
                int cs = c ^ ((n & 7) << 3);
                xT[n][cs]  = f2bf((&a.x)[j]);
                xeT[n][cs] = f2bf((&e.x)[j]);
            }
        }
    }
    __syncthreads();

    const unsigned short* lds = (w == 0) ? &xT[0][0] : &xeT[0][0];
    f4 acc[2][4] = {};
    #pragma unroll
    for (int kk = 0; kk < 8; ++kk) {
        bh8 bf[4];
        #pragma unroll
        for (int nf = 0; nf < 4; ++nf) {
            int n  = nf * 16 + l15;
            int c0 = (kk * 32 + l4 * 8) ^ ((n & 7) << 3);
            bf[nf] = *reinterpret_cast<const bh8*>(lds + n * 256 + c0);
        }
        #pragma unroll
        for (int nf = 0; nf < 4; ++nf) {
            acc[0][nf] = __builtin_amdgcn_mfma_f32_16x16x32_bf16(af[0][kk], bf[nf], acc[0][nf], 0, 0, 0);
            acc[1][nf] = __builtin_amdgcn_mfma_f32_16x16x32_bf16(af[1][kk], bf[nf], acc[1][nf], 0, 0, 0);
        }
    }

    if (w < 2) {
        unsigned short* dst = (w == 0 ? qb : kb) + (size_t)(b * NN) * C8;
        const float* bias = (w == 0) ? bq : bk;
        #pragma unroll
        for (int mf = 0; mf < 2; ++mf) {
            #pragma unroll
            for (int nf = 0; nf < 4; ++nf) {
                int n  = n0 + nf * 16 + l15;
                int oo = mf * 16 + l4 * 4;
                ushort4 pk;
                #pragma unroll
                for (int r = 0; r < 4; ++r) {
                    int o = oo + r;
                    float val = acc[mf][nf][r] + bias[o];
                    if (w == 1) val += hp[o * HH + (n >> 6)] + wp[o * WW + (n & 63)];
                    (&pk.x)[r] = f2bf(val);
                }
                *reinterpret_cast<ushort4*>(dst + (size_t)n * C8 + oo) = pk;
            }
        }
    } else {
        #pragma unroll
        for (int mf = 0; mf < 2; ++mf) {
            int cb = (w - 2) * 32 + mf * 16 + l4 * 4;
            #pragma unroll
            for (int r = 0; r < 4; ++r) {
                float bvv = bv[cb + r];
                #pragma unroll
                for (int nf = 0; nf < 4; ++nf) {
                    int n = n0 + nf * 16 + l15;
                    vv[(size_t)(b * CC + cb + r) * NN + n] = f2bf(acc[mf][nf][r] + bvv);
                }
            }
        }
    }
}

// ---------------------------------------------------------------------------
// Kernel 2: MFMA flash attention + fused epilogue  out = gamma*(P@V^T/l) + x
// Round-3 LDS shapes/swizzles (proven 0-conflict), but QBLK=32 with 4 waves
// -> grid 512 -> 2 independent blocks (barrier domains) per CU.
// Wave w: QK frags qg = w&1, ng in {2*(w>>1), 2*(w>>1)+1};
// softmax rows 8w..8w+7 (8 lanes/row, 8 cols each);
// PV channels [w*64, w*64+64).  18 MFMA / wave / 64-key tile (= R3 density).
// S[32][64] f32 (col ^= 4(q&7)); P[2][32][64] bf16 (col ^= 8(q&7)).
// ---------------------------------------------------------------------------
__global__ __launch_bounds__(256, 2) void attn_mfma_kernel(
    const unsigned short* __restrict__ qb, const unsigned short* __restrict__ kb,
    const unsigned short* __restrict__ v,  const float* __restrict__ x,
    const float* __restrict__ gamma, float* __restrict__ out)
{
    const int b    = blockIdx.x & 3;
    const int r0   = (blockIdx.x >> 2) << 5;    // q-tile base (32 rows)
    const int t    = threadIdx.x;
    const int w    = t >> 6;                    // 0..3
    const int lane = t & 63;
    const int l15  = lane & 15, l4 = lane >> 4;
    const int qg   = w & 1;
    const int ng0  = (w >> 1) * 2;              // 0 or 2

    __shared__ __align__(16) float S[32][64];              // 8 KB
    __shared__ __align__(16) unsigned short P[2][32][64];  // 8 KB
    __shared__ float a_lds[32];
    __shared__ float l_lds[32];

    // Q fragment (A-operand), held for whole kernel
    const bh8 qf = *reinterpret_cast<const bh8*>(
        qb + ((size_t)(b * NN) + r0 + qg * 16 + l15) * C8 + 8 * l4);

    // K base (B-operand, frags ng0 and ng0+1)
    const unsigned short* kbase = kb + ((size_t)(b * NN) + ng0 * 16 + l15) * C8 + 8 * l4;
    // V base: channel c = w*64 + cgi*16 + l15, key col tt*KBLK + ks*32 + 8*l4
    const unsigned short* vbase = v + ((size_t)(b * CC) + w * 64 + l15) * NN + 8 * l4;

    // softmax mapping: 8 rows/wave, 8 lanes/row, 8 cols/lane (R3 pattern)
    const int srow = 8 * w + (lane >> 3);
    const int sa   = lane & 7;
    const int scol0 = (8 * sa) ^ (4 * (srow & 7));
    float m_reg = -INFINITY, l_reg = 0.f;

    f4 acc[2][4] = {};   // [qgi][cgi]

    bh8 kf0 = *reinterpret_cast<const bh8*>(kbase);
    bh8 kf1 = *reinterpret_cast<const bh8*>(kbase + 16 * C8);

    for (int tt = 0; tt < NN / KBLK; ++tt) {
        // ---- QK^T ----
        f4 z = {0.f, 0.f, 0.f, 0.f};
        f4 s0 = __builtin_amdgcn_mfma_f32_16x16x32_bf16(qf, kf0, z, 0, 0, 0);
        f4 s1 = __builtin_amdgcn_mfma_f32_16x16x32_bf16(qf, kf1, z, 0, 0, 0);
        if (tt + 1 < NN / KBLK) {   // prefetch next K tile
            const unsigned short* kn = kbase + (size_t)(tt + 1) * KBLK * C8;
            kf0 = *reinterpret_cast<const bh8*>(kn);
            kf1 = *reinterpret_cast<const bh8*>(kn + 16 * C8);
        }
        #pragma unroll
        for (int r = 0; r < 4; ++r) {
            int q   = qg * 16 + l4 * 4 + r;
            int swz = 4 * (q & 7);
            S[q][(ng0 * 16 + l15) ^ swz]       = s0[r];
            S[q][((ng0 + 1) * 16 + l15) ^ swz] = s1[r];
        }
        __syncthreads();   // b1: S complete

        // prefetch V for this tile (latency hidden under softmax)
        bh8 vf[4][2];
        {
            const unsigned short* vt0 = vbase + (size_t)tt * KBLK;
            #pragma unroll
            for (int cgi = 0; cgi < 4; ++cgi)
                #pragma unroll
                for (int ks = 0; ks < 2; ++ks)
                    vf[cgi][ks] = *reinterpret_cast<const bh8*>(vt0 + (size_t)cgi * 16 * NN + ks * 32);
        }

        // ---- online softmax (8 rows per wave) ----
        f4 sv0 = *reinterpret_cast<const f4*>(&S[srow][scol0]);
        f4 sv1 = *reinterpret_cast<const f4*>(&S[srow][scol0 ^ 4]);
        float tmax = fmaxf(fmaxf(fmaxf(sv0[0], sv0[1]), fmaxf(sv0[2], sv0[3])),
                           fmaxf(fmaxf(sv1[0], sv1[1]), fmaxf(sv1[2], sv1[3])));
        tmax = fmaxf(tmax, __shfl_xor(tmax, 1));
        tmax = fmaxf(tmax, __shfl_xor(tmax, 2));
        tmax = fmaxf(tmax, __shfl_xor(tmax, 4));
        float mn    = fmaxf(m_reg, tmax);
        float alpha = __expf(m_reg - mn);
        float p0 = __expf(sv0[0] - mn), p1 = __expf(sv0[1] - mn);
        float p2 = __expf(sv0[2] - mn), p3 = __expf(sv0[3] - mn);
        float p4 = __expf(sv1[0] - mn), p5 = __expf(sv1[1] - mn);
        float p6 = __expf(sv1[2] - mn), p7 = __expf(sv1[3] - mn);
        float rs = ((p0 + p1) + (p2 + p3)) + ((p4 + p5) + (p6 + p7));
        rs += __shfl_xor(rs, 1);
        rs += __shfl_xor(rs, 2);
        rs += __shfl_xor(rs, 4);
        l_reg = l_reg * alpha + rs;
        m_reg = mn;
        if (sa == 0) a_lds[srow] = alpha;
        bh8 pb;
        pb[0] = (short)f2bf(p0); pb[1] = (short)f2bf(p1);
        pb[2] = (short)f2bf(p2); pb[3] = (short)f2bf(p3);
        pb[4] = (short)f2bf(p4); pb[5] = (short)f2bf(p5);
        pb[6] = (short)f2bf(p6); pb[7] = (short)f2bf(p7);
        *reinterpret_cast<bh8*>(&P[tt & 1][srow][(8 * sa) ^ (8 * (srow & 7))]) = pb;
        __syncthreads();   // b2: P + a_lds complete

        // ---- rescale ----
        f4 al0 = *reinterpret_cast<const f4*>(&a_lds[l4 * 4]);
        f4 al1 = *reinterpret_cast<const f4*>(&a_lds[16 + l4 * 4]);
        #pragma unroll
        for (int cgi = 0; cgi < 4; ++cgi) {
            #pragma unroll
            for (int r = 0; r < 4; ++r) {
                acc[0][cgi][r] *= al0[r];
                acc[1][cgi][r] *= al1[r];
            }
        }

        // ---- PV ----
        const unsigned short* Pb = &P[tt & 1][0][0];
        #pragma unroll
        for (int ks = 0; ks < 2; ++ks) {
            bh8 pa0 = *reinterpret_cast<const bh8*>(Pb + (l15)      * 64 + ((32 * ks + 8 * l4) ^ (8 * (l15 & 7))));
            bh8 pa1 = *reinterpret_cast<const bh8*>(Pb + (16 + l15) * 64 + ((32 * ks + 8 * l4) ^ (8 * (l15 & 7))));
            #pragma unroll
            for (int cgi = 0; cgi < 4; ++cgi) {
                acc[0][cgi] = __builtin_amdgcn_mfma_f32_16x16x32_bf16(pa0, vf[cgi][ks], acc[0][cgi], 0, 0, 0);
                acc[1][cgi] = __builtin_amdgcn_mfma_f32_16x16x32_bf16(pa1, vf[cgi][ks], acc[1][cgi], 0, 0, 0);
            }
        }
        // no barrier: S-writes(tt+1) are separated from S-reads(tt) by b2(tt);
        // P buffer (tt&1) next written at softmax(tt+2), after b1(tt+2).
    }

    // ---- epilogue: out = gamma*(acc/l) + x ----
    if (sa == 0) l_lds[srow] = l_reg;
    __syncthreads();
    const float g = gamma[0];
    f4 lv0 = *reinterpret_cast<const f4*>(&l_lds[l4 * 4]);
    f4 lv1 = *reinterpret_cast<const f4*>(&l_lds[16 + l4 * 4]);
    f4 li0, li1;
    #pragma unroll
    for (int r = 0; r < 4; ++r) { li0[r] = 1.f / lv0[r]; li1[r] = 1.f / lv1[r]; }
    #pragma unroll
    for (int qgi = 0; qgi < 2; ++qgi) {
        f4 li = qgi ? li1 : li0;
        #pragma unroll
        for (int cgi = 0; cgi < 4; ++cgi) {
            int c = w * 64 + cgi * 16 + l15;
            size_t idx = ((size_t)(b * CC) + c) * NN + r0 + qgi * 16 + l4 * 4;
            float4 xr = *reinterpret_cast<const float4*>(x + idx);
            float4 o4;
            o4.x = g * (acc[qgi][cgi][0] * li[0]) + xr.x;
            o4.y = g * (acc[qgi][cgi][1] * li[1]) + xr.y;
            o4.z = g * (acc[qgi][cgi][2] * li[2]) + xr.z;
            o4.w = g * (acc[qgi][cgi][3] * li[3]) + xr.w;
            *reinterpret_cast<float4*>(out + idx) = o4;
        }
    }
}

// ---------------------------------------------------------------------------
extern "C" void kernel_launch(void* const* d_in, const int* in_sizes, int n_in,
                              void* d_out, int out_size, void* d_ws, size_t ws_size,
                              hipStream_t stream)
{
    (void)in_sizes; (void)n_in; (void)out_size; (void)ws_size;

    const float* x   = (const float*)d_in[0];
    const float* xe  = (const float*)d_in[1];
    const float* Wq  = (const float*)d_in[2];
    const float* bq  = (const float*)d_in[3];
    const float* Wk  = (const float*)d_in[4];
    const float* bk  = (const float*)d_in[5];
    const float* Wv  = (const float*)d_in[6];
    const float* bv  = (const float*)d_in[7];
    const float* hp  = (const float*)d_in[8];
    const float* wp  = (const float*)d_in[9];
    const float* gam = (const float*)d_in[10];
    float* out = (float*)d_out;

    // workspace: qb bf16 [B][N][32] (1MB) | kb (1MB) | v bf16 [B][C][N] (8MB) | wb bf16 [320][256] (160KB)
    char* ws = (char*)d_ws;
    unsigned short* qb = (unsigned short*)ws;
    unsigned short* kb = (unsigned short*)(ws + (size_t)BB * NN * C8 * 2);
    unsigned short* v  = (unsigned short*)(ws + 2 * (size_t)BB * NN * C8 * 2);
    unsigned short* wbuf = (unsigned short*)(ws + 2 * (size_t)BB * NN * C8 * 2
                                                + (size_t)BB * CC * NN * 2);

    wconv_kernel<<<80, 256, 0, stream>>>(Wq, Wk, Wv, wbuf);
    proj_kernel<<<BB * (NN / 64), 640, 0, stream>>>(x, xe, wbuf, bq, bk, bv, hp, wp, qb, kb, v);
    attn_mfma_kernel<<<BB * (NN / QBLK), 256, 0, stream>>>(qb, kb, v, x, gam, out);
}

// Round 6
// 115.228 us; speedup vs baseline: 1.4047x; 1.3998x over previous
//
#include <hip/hip_runtime.h>
#include <hip/hip_bf16.h>
#include <math.h>

// Problem constants (AttentionDecoder: B,C,H,W = 4,256,64,64)
#define BB 4
#define CC 256
#define C8 32
#define HH 64
#define WW 64
#define NN 4096   // HH*WW
#define QBLK 64
#define KBLK 128  // two 64-key subtiles, R3-exact LDS geometry per subtile

typedef __attribute__((ext_vector_type(8))) short bh8;   // 8 x bf16 (4 VGPR)
typedef __attribute__((ext_vector_type(4))) float f4;    // MFMA accumulator

static __device__ __forceinline__ float bf2f(unsigned short u) {
    union { unsigned int u; float f; } v; v.u = ((unsigned int)u) << 16;
    return v.f;
}
static __device__ __forceinline__ unsigned short f2bf(float f) {
    union { float f; unsigned int u; } v; v.f = f;
    return (unsigned short)((v.u + 0x7FFFu + ((v.u >> 16) & 1u)) >> 16);
}

// ---------------------------------------------------------------------------
// Kernel 0: pack [Wq;Wk;Wv] -> bf16 wb[320][256]
// ---------------------------------------------------------------------------
__global__ __launch_bounds__(256) void wconv_kernel(
    const float* __restrict__ Wq, const float* __restrict__ Wk,
    const float* __restrict__ Wv, unsigned short* __restrict__ wb)
{
    int f = (blockIdx.x * 256 + threadIdx.x) * 4;   // element index, < 81920
    const float* src;
    if (f < 32 * 256)           src = Wq + f;
    else if (f < 64 * 256)      src = Wk + (f - 32 * 256);
    else                        src = Wv + (f - 64 * 256);
    float4 v = *reinterpret_cast<const float4*>(src);
    ushort4 o;
    o.x = f2bf(v.x); o.y = f2bf(v.y); o.z = f2bf(v.z); o.w = f2bf(v.w);
    *reinterpret_cast<ushort4*>(wb + f) = o;
}

// ---------------------------------------------------------------------------
// Kernel 1: fused Q/K/V projection GEMM (MFMA). (unchanged from round 3)
// ---------------------------------------------------------------------------
__global__ __launch_bounds__(640, 1) void proj_kernel(
    const float* __restrict__ x, const float* __restrict__ xe,
    const unsigned short* __restrict__ wb,
    const float* __restrict__ bq, const float* __restrict__ bk,
    const float* __restrict__ bv,
    const float* __restrict__ hp, const float* __restrict__ wp,
    unsigned short* __restrict__ qb, unsigned short* __restrict__ kb,
    unsigned short* __restrict__ vv)
{
    const int b  = blockIdx.x & 3;
    const int n0 = (blockIdx.x >> 2) << 6;
    const int t  = threadIdx.x;
    const int w  = t >> 6;                 // 0..9
    const int lane = t & 63;
    const int l15 = lane & 15, l4 = lane >> 4;

    __shared__ unsigned short xT[64][256];   // [n][c^swz]  32 KB
    __shared__ unsigned short xeT[64][256];  // 32 KB

    bh8 af[2][8];
    {
        const unsigned short* wrow = wb + (size_t)(w * 32 + l15) * 256 + l4 * 8;
        #pragma unroll
        for (int kk = 0; kk < 8; ++kk) {
            af[0][kk] = *reinterpret_cast<const bh8*>(wrow + kk * 32);
            af[1][kk] = *reinterpret_cast<const bh8*>(wrow + 16 * 256 + kk * 32);
        }
    }

    {
        const float* xb  = x  + (size_t)(b * CC) * NN + n0;
        const float* xeb = xe + (size_t)(b * CC) * NN + n0;
        for (int i = t; i < 4096; i += 640) {
            int c = i >> 4, n4 = (i & 15) << 2;
            float4 a = *reinterpret_cast<const float4*>(xb  + (size_t)c * NN + n4);
            float4 e = *reinterpret_cast<const float4*>(xeb + (size_t)c * NN + n4);
            #pragma unroll
            for (int j = 0; j < 4; ++j) {
                int n  = n4 + j;
                int cs = c ^ ((n & 7) << 3);
                xT[n][cs]  = f2bf((&a.x)[j]);
                xeT[n][cs] = f2bf((&e.x)[j]);
            }
        }
    }
    __syncthreads();

    const unsigned short* lds = (w == 0) ? &xT[0][0] : &xeT[0][0];
    f4 acc[2][4] = {};
    #pragma unroll
    for (int kk = 0; kk < 8; ++kk) {
        bh8 bf[4];
        #pragma unroll
        for (int nf = 0; nf < 4; ++nf) {
            int n  = nf * 16 + l15;
            int c0 = (kk * 32 + l4 * 8) ^ ((n & 7) << 3);
            bf[nf] = *reinterpret_cast<const bh8*>(lds + n * 256 + c0);
        }
        #pragma unroll
        for (int nf = 0; nf < 4; ++nf) {
            acc[0][nf] = __builtin_amdgcn_mfma_f32_16x16x32_bf16(af[0][kk], bf[nf], acc[0][nf], 0, 0, 0);
            acc[1][nf] = __builtin_amdgcn_mfma_f32_16x16x32_bf16(af[1][kk], bf[nf], acc[1][nf], 0, 0, 0);
        }
    }

    if (w < 2) {
        unsigned short* dst = (w == 0 ? qb : kb) + (size_t)(b * NN) * C8;
        const float* bias = (w == 0) ? bq : bk;
        #pragma unroll
        for (int mf = 0; mf < 2; ++mf) {
            #pragma unroll
            for (int nf = 0; nf < 4; ++nf) {
                int n  = n0 + nf * 16 + l15;
                int oo = mf * 16 + l4 * 4;
                ushort4 pk;
                #pragma unroll
                for (int r = 0; r < 4; ++r) {
                    int o = oo + r;
                    float val = acc[mf][nf][r] + bias[o];
                    if (w == 1) val += hp[o * HH + (n >> 6)] + wp[o * WW + (n & 63)];
                    (&pk.x)[r] = f2bf(val);
                }
                *reinterpret_cast<ushort4*>(dst + (size_t)n * C8 + oo) = pk;
            }
        }
    } else {
        #pragma unroll
        for (int mf = 0; mf < 2; ++mf) {
            int cb = (w - 2) * 32 + mf * 16 + l4 * 4;
            #pragma unroll
            for (int r = 0; r < 4; ++r) {
                float bvv = bv[cb + r];
                #pragma unroll
                for (int nf = 0; nf < 4; ++nf) {
                    int n = n0 + nf * 16 + l15;
                    vv[(size_t)(b * CC + cb + r) * NN + n] = f2bf(acc[mf][nf][r] + bvv);
                }
            }
        }
    }
}

// ---------------------------------------------------------------------------
// Kernel 2: MFMA flash attention + fused epilogue  out = gamma*(P@V^T/l) + x
// R3 geometry (QBLK=64, 512 thr, grid 256, 64-col 0-conflict swizzles) with:
//  - KBLK=128 as 2 x 64-key subtiles -> barriers halved (2 per 128 keys)
//  - V/K register double-buffer across iterations (latency off critical path)
//  - s_setprio(1) around PV MFMA cluster
// Wave w: QK frags (qg0,qg0+1) x (half h, ng = w&3); softmax rows 8w..8w+7;
// PV channels [w*32, w*32+32), 32 MFMA per iter.
// ---------------------------------------------------------------------------
__global__ __launch_bounds__(512, 2) void attn_mfma_kernel(
    const unsigned short* __restrict__ qb, const unsigned short* __restrict__ kb,
    const unsigned short* __restrict__ v,  const float* __restrict__ x,
    const float* __restrict__ gamma, float* __restrict__ out)
{
    const int b    = blockIdx.x & 3;
    const int r0   = (blockIdx.x >> 2) << 6;    // q-tile base (64 rows)
    const int t    = threadIdx.x;
    const int w    = t >> 6;
    const int lane = t & 63;
    const int l15  = lane & 15, l4 = lane >> 4;
    const int ngw  = w & 3;
    const int qg0  = (w >> 2) * 2;              // 0 or 2

    __shared__ __align__(16) float S[2][64][64];             // 32 KB
    __shared__ __align__(16) unsigned short P[2][64][64];    // 16 KB
    __shared__ float a_lds[64];
    __shared__ float l_lds[64];

    // Q fragments (A-operand), held for whole kernel
    const bh8 qf0 = *reinterpret_cast<const bh8*>(
        qb + ((size_t)(b * NN) + r0 + qg0 * 16 + l15) * C8 + 8 * l4);
    const bh8 qf1 = *reinterpret_cast<const bh8*>(
        qb + ((size_t)(b * NN) + r0 + (qg0 + 1) * 16 + l15) * C8 + 8 * l4);

    // K base: frag for half h of tile tt at kbase + (tt*128 + h*64)*C8
    const unsigned short* kbase = kb + ((size_t)(b * NN) + ngw * 16 + l15) * C8 + 8 * l4;
    // V base: chan c = w*32 + cgi*16 + l15; key = tt*128 + h*64 + ks*32 + 8*l4
    const unsigned short* vbase = v + ((size_t)(b * CC) + w * 32 + l15) * NN + 8 * l4;

    // softmax mapping: 8 rows/wave, 8 lanes/row, 8 cols/lane (R3 pattern)
    const int srow  = 8 * w + (lane >> 3);
    const int sa    = lane & 7;
    const int scol0 = (8 * sa) ^ (4 * (srow & 7));
    const int pcol  = (8 * sa) ^ (8 * (srow & 7));
    float m_reg = -INFINITY, l_reg = 0.f;

    f4 acc[4][2] = {};   // [qgi][cgi]

    // double-buffered K/V fragments
    bh8 kfA[2], kfB[2];          // [half]
    bh8 vfA[2][2][2], vfB[2][2][2];  // [half][cgi][ks]

    kfA[0] = *reinterpret_cast<const bh8*>(kbase);
    kfA[1] = *reinterpret_cast<const bh8*>(kbase + 64 * C8);
    #pragma unroll
    for (int h = 0; h < 2; ++h)
        #pragma unroll
        for (int cgi = 0; cgi < 2; ++cgi)
            #pragma unroll
            for (int ks = 0; ks < 2; ++ks)
                vfA[h][cgi][ks] = *reinterpret_cast<const bh8*>(
                    vbase + h * 64 + ks * 32 + (size_t)cgi * 16 * NN);

#define ATTN_ITER(VC, VN, KC, KN, TT)                                           \
    {                                                                           \
        f4 z = {0.f, 0.f, 0.f, 0.f};                                            \
        f4 s00 = __builtin_amdgcn_mfma_f32_16x16x32_bf16(qf0, KC[0], z, 0, 0, 0); \
        f4 s10 = __builtin_amdgcn_mfma_f32_16x16x32_bf16(qf1, KC[0], z, 0, 0, 0); \
        f4 s01 = __builtin_amdgcn_mfma_f32_16x16x32_bf16(qf0, KC[1], z, 0, 0, 0); \
        f4 s11 = __builtin_amdgcn_mfma_f32_16x16x32_bf16(qf1, KC[1], z, 0, 0, 0); \
        _Pragma("unroll")                                                       \
        for (int r = 0; r < 4; ++r) {                                           \
            int q0 = qg0 * 16 + l4 * 4 + r;                                     \
            int q1 = q0 + 16;                                                   \
            int c0 = (ngw * 16 + l15) ^ (4 * (q0 & 7));                         \
            int c1 = (ngw * 16 + l15) ^ (4 * (q1 & 7));                         \
            S[0][q0][c0] = s00[r];                                              \
            S[0][q1][c1] = s10[r];                                              \
            S[1][q0][c0] = s01[r];                                              \
            S[1][q1][c1] = s11[r];                                              \
        }                                                                       \
        __syncthreads(); /* b1: S complete */                                   \
        if ((TT) + 1 < NN / KBLK) { /* prefetch next K/V tile (1 iter cover) */ \
            const unsigned short* kn = kbase + (size_t)((TT) + 1) * KBLK * C8;  \
            KN[0] = *reinterpret_cast<const bh8*>(kn);                          \
            KN[1] = *reinterpret_cast<const bh8*>(kn + 64 * C8);                \
            const unsigned short* vn = vbase + (size_t)((TT) + 1) * KBLK;       \
            _Pragma("unroll")                                                   \
            for (int h = 0; h < 2; ++h)                                         \
                _Pragma("unroll")                                               \
                for (int cgi = 0; cgi < 2; ++cgi)                               \
                    _Pragma("unroll")                                           \
                    for (int ks = 0; ks < 2; ++ks)                              \
                        VN[h][cgi][ks] = *reinterpret_cast<const bh8*>(         \
                            vn + h * 64 + ks * 32 + (size_t)cgi * 16 * NN);     \
        }                                                                       \
        /* online softmax over both halves */                                   \
        f4 sv0 = *reinterpret_cast<const f4*>(&S[0][srow][scol0]);              \
        f4 sv1 = *reinterpret_cast<const f4*>(&S[0][srow][scol0 ^ 4]);          \
        f4 sv2 = *reinterpret_cast<const f4*>(&S[1][srow][scol0]);              \
        f4 sv3 = *reinterpret_cast<const f4*>(&S[1][srow][scol0 ^ 4]);          \
        float tmax = fmaxf(                                                     \
            fmaxf(fmaxf(fmaxf(sv0[0], sv0[1]), fmaxf(sv0[2], sv0[3])),          \
                  fmaxf(fmaxf(sv1[0], sv1[1]), fmaxf(sv1[2], sv1[3]))),         \
            fmaxf(fmaxf(fmaxf(sv2[0], sv2[1]), fmaxf(sv2[2], sv2[3])),          \
                  fmaxf(fmaxf(sv3[0], sv3[1]), fmaxf(sv3[2], sv3[3]))));        \
        tmax = fmaxf(tmax, __shfl_xor(tmax, 1));                                \
        tmax = fmaxf(tmax, __shfl_xor(tmax, 2));                                \
        tmax = fmaxf(tmax, __shfl_xor(tmax, 4));                                \
        float mn    = fmaxf(m_reg, tmax);                                       \
        float alpha = __expf(m_reg - mn);                                       \
        float e0 = __expf(sv0[0] - mn), e1 = __expf(sv0[1] - mn);               \
        float e2 = __expf(sv0[2] - mn), e3 = __expf(sv0[3] - mn);               \
        float e4 = __expf(sv1[0] - mn), e5 = __expf(sv1[1] - mn);               \
        float e6 = __expf(sv1[2] - mn), e7 = __expf(sv1[3] - mn);               \
        float f0 = __expf(sv2[0] - mn), f1 = __expf(sv2[1] - mn);               \
        float f2 = __expf(sv2[2] - mn), f3 = __expf(sv2[3] - mn);               \
        float f4_ = __expf(sv3[0] - mn), f5 = __expf(sv3[1] - mn);              \
        float f6 = __expf(sv3[2] - mn), f7 = __expf(sv3[3] - mn);               \
        float rs = (((e0 + e1) + (e2 + e3)) + ((e4 + e5) + (e6 + e7)))          \
                 + (((f0 + f1) + (f2 + f3)) + ((f4_ + f5) + (f6 + f7)));        \
        rs += __shfl_xor(rs, 1);                                                \
        rs += __shfl_xor(rs, 2);                                                \
        rs += __shfl_xor(rs, 4);                                                \
        l_reg = l_reg * alpha + rs;                                             \
        m_reg = mn;                                                             \
        if (sa == 0) a_lds[srow] = alpha;                                       \
        bh8 pb0, pb1;                                                           \
        pb0[0] = (short)f2bf(e0); pb0[1] = (short)f2bf(e1);                     \
        pb0[2] = (short)f2bf(e2); pb0[3] = (short)f2bf(e3);                     \
        pb0[4] = (short)f2bf(e4); pb0[5] = (short)f2bf(e5);                     \
        pb0[6] = (short)f2bf(e6); pb0[7] = (short)f2bf(e7);                     \
        pb1[0] = (short)f2bf(f0); pb1[1] = (short)f2bf(f1);                     \
        pb1[2] = (short)f2bf(f2); pb1[3] = (short)f2bf(f3);                     \
        pb1[4] = (short)f2bf(f4_); pb1[5] = (short)f2bf(f5);                    \
        pb1[6] = (short)f2bf(f6); pb1[7] = (short)f2bf(f7);                     \
        *reinterpret_cast<bh8*>(&P[0][srow][pcol]) = pb0;                       \
        *reinterpret_cast<bh8*>(&P[1][srow][pcol]) = pb1;                       \
        __syncthreads(); /* b2: P + a_lds complete */                           \
        _Pragma("unroll")                                                       \
        for (int qgi = 0; qgi < 4; ++qgi) {                                     \
            f4 al = *reinterpret_cast<const f4*>(&a_lds[qgi * 16 + l4 * 4]);    \
            _Pragma("unroll")                                                   \
            for (int cgi = 0; cgi < 2; ++cgi) {                                 \
                acc[qgi][cgi][0] *= al[0];                                      \
                acc[qgi][cgi][1] *= al[1];                                      \
                acc[qgi][cgi][2] *= al[2];                                      \
                acc[qgi][cgi][3] *= al[3];                                      \
            }                                                                   \
        }                                                                       \
        __builtin_amdgcn_s_setprio(1);                                          \
        _Pragma("unroll")                                                       \
        for (int h = 0; h < 2; ++h) {                                           \
            _Pragma("unroll")                                                   \
            for (int ks = 0; ks < 2; ++ks) {                                    \
                bh8 pa[4];                                                      \
                _Pragma("unroll")                                               \
                for (int qgi = 0; qgi < 4; ++qgi) {                             \
                    int q   = qgi * 16 + l15;                                   \
                    int col = (32 * ks + 8 * l4) ^ (8 * (q & 7));               \
                    pa[qgi] = *reinterpret_cast<const bh8*>(&P[h][q][col]);     \
                }                                                               \
                _Pragma("unroll")                                               \
                for (int qgi = 0; qgi < 4; ++qgi)                               \
                    acc[qgi][0] = __builtin_amdgcn_mfma_f32_16x16x32_bf16(      \
                        pa[qgi], VC[h][0][ks], acc[qgi][0], 0, 0, 0);           \
                _Pragma("unroll")                                               \
                for (int qgi = 0; qgi < 4; ++qgi)                               \
                    acc[qgi][1] = __builtin_amdgcn_mfma_f32_16x16x32_bf16(      \
                        pa[qgi], VC[h][1][ks], acc[qgi][1], 0, 0, 0);           \
            }                                                                   \
        }                                                                       \
        __builtin_amdgcn_s_setprio(0);                                          \
    }

    for (int tt = 0; tt < NN / KBLK; tt += 2) {
        ATTN_ITER(vfA, vfB, kfA, kfB, tt);
        ATTN_ITER(vfB, vfA, kfB, kfA, tt + 1);
    }
#undef ATTN_ITER

    // ---- epilogue: out = gamma*(acc/l) + x ----
    if (sa == 0) l_lds[srow] = l_reg;
    __syncthreads();
    const float g = gamma[0];
    #pragma unroll
    for (int qgi = 0; qgi < 4; ++qgi) {
        f4 lv = *reinterpret_cast<const f4*>(&l_lds[qgi * 16 + l4 * 4]);
        f4 li;
        li[0] = 1.f / lv[0]; li[1] = 1.f / lv[1];
        li[2] = 1.f / lv[2]; li[3] = 1.f / lv[3];
        #pragma unroll
        for (int cgi = 0; cgi < 2; ++cgi) {
            int c = w * 32 + cgi * 16 + l15;
            size_t idx = ((size_t)(b * CC) + c) * NN + r0 + qgi * 16 + l4 * 4;
            float4 xr = *reinterpret_cast<const float4*>(x + idx);
            float4 o4;
            o4.x = g * (acc[qgi][cgi][0] * li[0]) + xr.x;
            o4.y = g * (acc[qgi][cgi][1] * li[1]) + xr.y;
            o4.z = g * (acc[qgi][cgi][2] * li[2]) + xr.z;
            o4.w = g * (acc[qgi][cgi][3] * li[3]) + xr.w;
            *reinterpret_cast<float4*>(out + idx) = o4;
        }
    }
}

// ---------------------------------------------------------------------------
extern "C" void kernel_launch(void* const* d_in, const int* in_sizes, int n_in,
                              void* d_out, int out_size, void* d_ws, size_t ws_size,
                              hipStream_t stream)
{
    (void)in_sizes; (void)n_in; (void)out_size; (void)ws_size;

    const float* x   = (const float*)d_in[0];
    const float* xe  = (const float*)d_in[1];
    const float* Wq  = (const float*)d_in[2];
    const float* bq  = (const float*)d_in[3];
    const float* Wk  = (const float*)d_in[4];
    const float* bk  = (const float*)d_in[5];
    const float* Wv  = (const float*)d_in[6];
    const float* bv  = (const float*)d_in[7];
    const float* hp  = (const float*)d_in[8];
    const float* wp  = (const float*)d_in[9];
    const float* gam = (const float*)d_in[10];
    float* out = (float*)d_out;

    // workspace: qb bf16 [B][N][32] (1MB) | kb (1MB) | v bf16 [B][C][N] (8MB) | wb bf16 [320][256] (160KB)
    char* ws = (char*)d_ws;
    unsigned short* qb = (unsigned short*)ws;
    unsigned short* kb = (unsigned short*)(ws + (size_t)BB * NN * C8 * 2);
    unsigned short* v  = (unsigned short*)(ws + 2 * (size_t)BB * NN * C8 * 2);
    unsigned short* wbuf = (unsigned short*)(ws + 2 * (size_t)BB * NN * C8 * 2
                                                + (size_t)BB * CC * NN * 2);

    wconv_kernel<<<80, 256, 0, stream>>>(Wq, Wk, Wv, wbuf);
    proj_kernel<<<BB * (NN / 64), 640, 0, stream>>>(x, xe, wbuf, bq, bk, bv, hp, wp, qb, kb, v);
    attn_mfma_kernel<<<BB * (NN / QBLK), 512, 0, stream>>>(qb, kb, v, x, gam, out);
}